// Round 9
// baseline (859.191 us; speedup 1.0000x reference)
//
#include <hip/hip_runtime.h>
#include <math.h>
#include <stdint.h>

typedef _Float16 half_t;
typedef _Float16 half8 __attribute__((ext_vector_type(8)));
typedef __fp16 fp16x2 __attribute__((ext_vector_type(2)));
typedef float floatx4 __attribute__((ext_vector_type(4)));
typedef float floatx16 __attribute__((ext_vector_type(16)));

constexpr float BN_EPS_C = 1e-5f;
constexpr float RES_SCALE_C = 0.70710678118654752f;
constexpr float GAMMA_C = 1.5f;
#define B_TOT 65536

// LDS-only barrier: does NOT drain vmcnt, so global prefetches stay in flight.
// Safe here because all cross-wave data flows through LDS (lgkm-tracked).
__device__ __forceinline__ void lgkm_barrier() {
    __asm__ volatile("s_waitcnt lgkmcnt(0)\n\ts_barrier" ::: "memory");
}

// ---------------- packed (hi,lo) fp16-pair helpers ----------------
__device__ __forceinline__ uint32_t pack2(float y) {
    const half_t h = (half_t)y;
    const half_t l = (half_t)(y - (float)h);
    union { half_t f; unsigned short u; } a, b; a.f = h; b.f = l;
    return (uint32_t)a.u | ((uint32_t)b.u << 16);
}
__device__ __forceinline__ void unpack2(uint32_t v, half_t& h, half_t& l) {
    union { unsigned short u; half_t f; } a, b;
    a.u = (unsigned short)(v & 0xffffu); b.u = (unsigned short)(v >> 16);
    h = a.f; l = b.f;
}
// paired split via packed RTZ converts (lo plane captures the RTZ residual; ~2^-21 rel)
__device__ __forceinline__ void split_pair(float y0, float y1, half_t& h0, half_t& l0, half_t& h1, half_t& l1) {
    fp16x2 hh = __builtin_amdgcn_cvt_pkrtz(y0, y1);
    fp16x2 ll = __builtin_amdgcn_cvt_pkrtz(y0 - (float)hh.x, y1 - (float)hh.y);
    h0 = (half_t)hh.x; l0 = (half_t)ll.x; h1 = (half_t)hh.y; l1 = (half_t)ll.y;
}
__device__ __forceinline__ void pack2_pair(float y0, float y1, uint32_t& w0, uint32_t& w1) {
    fp16x2 hh = __builtin_amdgcn_cvt_pkrtz(y0, y1);
    fp16x2 ll = __builtin_amdgcn_cvt_pkrtz(y0 - (float)hh.x, y1 - (float)hh.y);
    const uint32_t hb = __builtin_bit_cast(uint32_t, hh);
    const uint32_t lb = __builtin_bit_cast(uint32_t, ll);
    w0 = (hb & 0xffffu) | (lb << 16);
    w1 = (hb >> 16) | (lb & 0xffff0000u);
}

// ---------------- W split+repack (fragment-major 8-granule, hi/lo planes) ----------------
__global__ void wsplit_kernel(const float* __restrict__ sh_W0, const float* __restrict__ sh_W1,
                              const float* __restrict__ init_W, const float* __restrict__ step_W,
                              half_t* __restrict__ Wh, half_t* __restrict__ Wl)
{
    const int b = blockIdx.x, n = threadIdx.x;
    const float* src; int k; size_t base;
    if (b < 320)      { src = sh_W0;           k = b;       base = 0; }
    else if (b < 448) { src = sh_W1;           k = b - 320; base = 81920; }
    else if (b < 576) { src = init_W;          k = b - 448; base = 114688; }
    else if (b < 704) { src = init_W + 32768;  k = b - 576; base = 147456; }
    else {
        int j = (b - 704) >> 7; k = (b - 704) & 127;
        src = step_W + (size_t)j * 32768; base = 180224 + (size_t)j * 32768;
    }
    const float v = src[k * 256 + n];
    const half_t hi = (half_t)v;
    const half_t lo = (half_t)(v - (float)hi);
    const size_t idx = base + (size_t)(((k >> 3) * 256 + n) * 8 + (k & 7));
    Wh[idx] = hi; Wl[idx] = lo;
}

__global__ void wsplit_att_kernel(const float* __restrict__ att_W,
                                  half_t* __restrict__ aWh, half_t* __restrict__ aWl)
{
    const int b = blockIdx.x;        // step*64 + k
    const int n = threadIdx.x;       // 0..79
    const int step = b >> 6, k = b & 63;
    const float v = att_W[(size_t)b * 80 + n];
    const half_t h = (half_t)v;
    const half_t l = (half_t)(v - (float)h);
    const size_t idx = (size_t)step * 5120 + (size_t)(((k >> 3) * 80 + n) * 8 + (k & 7));
    aWh[idx] = h; aWl[idx] = l;
}

__global__ void embed_bn_kernel(const float* __restrict__ x_num, const int* __restrict__ x_cat,
                                const float* __restrict__ emb_W, const float* __restrict__ in_bn,
                                uint32_t* __restrict__ xp)
{
    const int idx = blockIdx.x * 256 + threadIdx.x;
    const int s = idx / 320, j = idx - s * 320;
    float v;
    if (j < 64) v = x_num[(size_t)s * 64 + j];
    else {
        const int c = (j - 64) >> 4, e = (j - 64) & 15;
        v = emb_W[(size_t)(c * 1000 + x_cat[(size_t)s * 16 + c]) * 16 + e];
    }
    const float val = (v - in_bn[640 + j]) * (in_bn[j] * __frsqrt_rn(in_bn[960 + j] + BN_EPS_C)) + in_bn[320 + j];
    xp[idx] = pack2(val);
}

__device__ __forceinline__ void bn_fold(const float* __restrict__ bn, const float* __restrict__ bias,
                                        int c, float& sc, float& sh)
{
    sc = bn[c] * __frsqrt_rn(bn[768 + c] + BN_EPS_C);
    sh = fmaf(bias[c] - bn[512 + c], sc, bn[256 + c]);
}

__device__ __forceinline__ float glu_val(float accO, float accG,
                                         float sc_o, float sh_o, float sc_g, float sh_g)
{
    const float o = fmaf(accO, sc_o, sh_o);
    const float g = fmaf(accG, sc_g, sh_g);
    const float e = __expf(-g);
    return o * __builtin_amdgcn_rcpf(1.f + e);
}

#define MFMA32(A, B, C) C = __builtin_amdgcn_mfma_f32_32x32x16_f16(A, B, C, 0, 0, 0)
#define MFMA16(A, B, C) C = __builtin_amdgcn_mfma_f32_16x16x32_f16(A, B, C, 0, 0, 0)

// K=128 layer accumulate from H planes; software-pipelined (W + A double-buffered).
__device__ __forceinline__ void layer_accum(const half_t (*H_h)[136], const half_t (*H_l)[136],
                                            const half_t* __restrict__ Wh, const half_t* __restrict__ Wl,
                                            size_t off, int n32, int k8, int no, int rot,
                                            floatx16* accO, floatx16* accG)
{
    half8 bo_h[2], bg_h[2], bo_l[2], bg_l[2];
    half8 a_h[2][4], a_l[2][4];
    {
        const int sl8 = rot & 7;
        const size_t wo = off + (size_t)((sl8 * 2 + k8) * 256 + no + n32) * 8;
        bo_h[0] = *(const half8*)(Wh + wo);
        bg_h[0] = *(const half8*)(Wh + wo + 1024);
        bo_l[0] = *(const half8*)(Wl + wo);
        bg_l[0] = *(const half8*)(Wl + wo + 1024);
#pragma unroll
        for (int mt = 0; mt < 4; ++mt) {
            a_h[0][mt] = *(const half8*)&H_h[mt * 32 + n32][sl8 * 16 + k8 * 8];
            a_l[0][mt] = *(const half8*)&H_l[mt * 32 + n32][sl8 * 16 + k8 * 8];
        }
    }
#pragma unroll
    for (int s = 0; s < 8; ++s) {
        const int cur = s & 1, nxt = cur ^ 1;
        if (s < 7) {
            const int nsl = (s + 1 + rot) & 7;
            const size_t wo = off + (size_t)((nsl * 2 + k8) * 256 + no + n32) * 8;
            bo_h[nxt] = *(const half8*)(Wh + wo);
            bg_h[nxt] = *(const half8*)(Wh + wo + 1024);
            bo_l[nxt] = *(const half8*)(Wl + wo);
            bg_l[nxt] = *(const half8*)(Wl + wo + 1024);
#pragma unroll
            for (int mt = 0; mt < 4; ++mt) {
                a_h[nxt][mt] = *(const half8*)&H_h[mt * 32 + n32][nsl * 16 + k8 * 8];
                a_l[nxt][mt] = *(const half8*)&H_l[mt * 32 + n32][nsl * 16 + k8 * 8];
            }
        }
#pragma unroll
        for (int mt = 0; mt < 4; ++mt) {
            MFMA32(a_h[cur][mt], bo_h[cur], accO[mt]); MFMA32(a_h[cur][mt], bg_h[cur], accG[mt]);
            MFMA32(a_l[cur][mt], bo_h[cur], accO[mt]); MFMA32(a_l[cur][mt], bg_h[cur], accG[mt]);
            MFMA32(a_h[cur][mt], bo_l[cur], accO[mt]); MFMA32(a_h[cur][mt], bg_l[cur], accG[mt]);
        }
    }
}

// ---------------- fused (att+sparsemax) + FT chain, 128 samples/block ----------------
template<bool MASK>
__global__ __launch_bounds__(256, 2)
void ft_chain(const uint32_t* __restrict__ xp, uint32_t* __restrict__ avp,
              const half_t* __restrict__ Wh, const half_t* __restrict__ Wl,
              const half_t* __restrict__ aWh, const half_t* __restrict__ aWl,
              const float* __restrict__ att_b, const float* __restrict__ att_bn,
              float* __restrict__ prior,
              const float* __restrict__ b1, const float* __restrict__ bn1,
              const float* __restrict__ b2, const float* __restrict__ bn2,
              const float* __restrict__ b3, const float* __restrict__ bn3,
              const float* __restrict__ b4, const float* __restrict__ bn4,
              size_t w3_off, size_t w4_off,
              float* __restrict__ ds, int wmode_last, int step)
{
    // LDS region plan (79872 B total, overlaid in time):
    //  [0,43008)        mgs float[128][84]      (mask; live att-z -> end of L1 staging)
    //  [43008,79872)    As planes [128][72]x2   (L1 chunk tile) / Apk uint32[128][68] (att stage)
    //  [0,69632)        H planes [128][136]x2   (written at L1 epilogue, after all above dead)
    __shared__ __align__(16) char smem[79872];
    float    (*mgs)[84]  = (float    (*)[84])smem;
    half_t   (*As_h)[72] = (half_t   (*)[72])(smem + 43008);
    half_t   (*As_l)[72] = (half_t   (*)[72])(smem + 61440);
    uint32_t (*Apk)[68]  = (uint32_t (*)[68])(smem + 43008);
    half_t   (*H_h)[136] = (half_t   (*)[136])smem;
    half_t   (*H_l)[136] = (half_t   (*)[136])(smem + 34816);

    const int t = threadIdx.x;
    const int s0 = blockIdx.x * 128;
    const int w = t >> 6, lane = t & 63;
    const int n32 = lane & 31, k8 = lane >> 5;
    const int quad = lane >> 4, l16 = lane & 15;
    const int no = 32 * w;
    const int half_id = (blockIdx.x >> 8) & 1;
    const int row = t >> 1, k0 = (t & 1) * 32;

    if (MASK) {
        // ---- stage avp (packed) -> Apk
        {
            const uint4* src = (const uint4*)(avp + (size_t)(s0 + row) * 64 + k0);
            uint4* dst = (uint4*)&Apk[row][k0];
#pragma unroll
            for (int q = 0; q < 8; ++q) dst[q] = src[q];
        }
        lgkm_barrier();
        // ---- z = BN(a@attW + b) * prior
        floatx4 zacc[2][5];
#pragma unroll
        for (int mt = 0; mt < 2; ++mt)
#pragma unroll
            for (int nt = 0; nt < 5; ++nt) zacc[mt][nt] = (floatx4){0.f, 0.f, 0.f, 0.f};
#pragma unroll
        for (int kc = 0; kc < 64; kc += 32) {
            half8 a_h[2], a_l[2];
#pragma unroll
            for (int mt = 0; mt < 2; ++mt) {
                uint32_t wv[8];
                *(uint4*)&wv[0] = *(const uint4*)&Apk[w * 32 + mt * 16 + l16][kc + quad * 8];
                *(uint4*)&wv[4] = *(const uint4*)&Apk[w * 32 + mt * 16 + l16][kc + quad * 8 + 4];
#pragma unroll
                for (int j = 0; j < 8; ++j) { half_t h, l; unpack2(wv[j], h, l); a_h[mt][j] = h; a_l[mt][j] = l; }
            }
            const int kq = (kc >> 3) + quad;
#pragma unroll
            for (int nt = 0; nt < 5; ++nt) {
                const size_t wi = (size_t)(kq * 80 + nt * 16 + l16) * 8;
                const half8 b_h = *(const half8*)(aWh + wi);
                const half8 b_l = *(const half8*)(aWl + wi);
#pragma unroll
                for (int mt = 0; mt < 2; ++mt) {
                    MFMA16(a_h[mt], b_h, zacc[mt][nt]);
                    MFMA16(a_l[mt], b_h, zacc[mt][nt]);
                    MFMA16(a_h[mt], b_l, zacc[mt][nt]);
                }
            }
        }
        float preg[2][5][4];
#pragma unroll
        for (int nt = 0; nt < 5; ++nt) {
            const int c = nt * 16 + l16;
            const float sc = att_bn[c] * __frsqrt_rn(att_bn[240 + c] + BN_EPS_C);
            const float sh = fmaf(att_b[c] - att_bn[160 + c], sc, att_bn[80 + c]);
#pragma unroll
            for (int mt = 0; mt < 2; ++mt)
#pragma unroll
                for (int r = 0; r < 4; ++r) {
                    const int sl = w * 32 + mt * 16 + quad * 4 + r;
                    const float pr = (step == 0) ? 1.f : prior[(size_t)(s0 + sl) * 80 + c];
                    preg[mt][nt][r] = pr;
                    mgs[sl][c] = fmaf(zacc[mt][nt][r], sc, sh) * pr;
                }
        }
        lgkm_barrier();
        // ---- bisection sparsemax: 2 threads/sample, 40 groups each
        {
            const int samp = row, j0 = (t & 1) * 40;
            float zj[40], zmax = -1e30f;
#pragma unroll
            for (int j = 0; j < 40; ++j) { zj[j] = mgs[samp][j0 + j]; zmax = fmaxf(zmax, zj[j]); }
            zmax = fmaxf(zmax, __shfl_xor(zmax, 1));
            float lo = zmax - 1.f, hi = zmax;
#pragma unroll 1
            for (int it = 0; it < 22; ++it) {
                const float mid = 0.5f * (lo + hi);
                float ssum = 0.f;
#pragma unroll
                for (int j = 0; j < 40; ++j) ssum += fmaxf(zj[j] - mid, 0.f);
                ssum += __shfl_xor(ssum, 1);
                if (ssum >= 1.f) lo = mid; else hi = mid;
            }
            const float tau = 0.5f * (lo + hi);
#pragma unroll
            for (int j = 0; j < 40; ++j) mgs[samp][j0 + j] = fmaxf(zj[j] - tau, 0.f);
        }
        lgkm_barrier();
        // ---- prior update
#pragma unroll
        for (int nt = 0; nt < 5; ++nt) {
            const int c = nt * 16 + l16;
#pragma unroll
            for (int mt = 0; mt < 2; ++mt)
#pragma unroll
                for (int r = 0; r < 4; ++r) {
                    const int sl = w * 32 + mt * 16 + quad * 4 + r;
                    prior[(size_t)(s0 + sl) * 80 + c] = preg[mt][nt][r] * (GAMMA_C - mgs[sl][c]);
                }
        }
    }

    // ---------------- L1: K=320 (5 chunks of 64), masked staging, prefetched
    floatx16 accO[4], accG[4];
#pragma unroll
    for (int i = 0; i < 4; ++i) { accO[i] = (floatx16)(0.f); accG[i] = (floatx16)(0.f); }

    const uint32_t* arow = xp + (size_t)(s0 + row) * 320 + k0;
    uint32_t pfw[32];
    int ic = half_id * 2;
#pragma unroll
    for (int q = 0; q < 8; ++q)
        *(uint4*)&pfw[q * 4] = *(const uint4*)(arow + ic * 64 + q * 4);

    half8 wbo_h[2], wbg_h[2], wbo_l[2], wbg_l[2];

#pragma unroll 1
    for (int i = 0; i < 5; ++i) {
        // preload this chunk's slice-0 W before the barriers: flies during staging
        {
            const int kq = ic * 8 + k8;
            const size_t wo = (size_t)(kq * 256 + no + n32) * 8;
            wbo_h[0] = *(const half8*)(Wh + wo);
            wbg_h[0] = *(const half8*)(Wh + wo + 1024);
            wbo_l[0] = *(const half8*)(Wl + wo);
            wbg_l[0] = *(const half8*)(Wl + wo + 1024);
        }
        lgkm_barrier();                        // prev chunk LDS reads done
        {
            const int kb = ic * 64 + k0;
            float mA = 1.f, mB = 1.f;
            if (MASK && ic != 0) {
                mA = mgs[row][64 + ((kb - 64) >> 4)];
                mB = mgs[row][64 + ((kb - 48) >> 4)];
            }
#pragma unroll
            for (int q = 0; q < 4; ++q) {
                half8 hh, ll;
                if (MASK && ic == 0) {
                    const float4 m0q = *(const float4*)&mgs[row][kb + q * 8];
                    const float4 m1q = *(const float4*)&mgs[row][kb + q * 8 + 4];
                    const float mm[8] = {m0q.x, m0q.y, m0q.z, m0q.w, m1q.x, m1q.y, m1q.z, m1q.w};
#pragma unroll
                    for (int j = 0; j < 8; ++j) {
                        half_t h, l; unpack2(pfw[q * 8 + j], h, l);
                        const float v = ((float)h + (float)l) * mm[j];
                        const half_t nh = (half_t)v;
                        hh[j] = nh; ll[j] = (half_t)(v - (float)nh);
                    }
                } else if (MASK) {
                    const float m = (q < 2) ? mA : mB;
#pragma unroll
                    for (int j = 0; j < 8; ++j) {
                        half_t h, l; unpack2(pfw[q * 8 + j], h, l);
                        const float v = ((float)h + (float)l) * m;
                        const half_t nh = (half_t)v;
                        hh[j] = nh; ll[j] = (half_t)(v - (float)nh);
                    }
                } else {
#pragma unroll
                    for (int j = 0; j < 8; ++j) { half_t h, l; unpack2(pfw[q * 8 + j], h, l); hh[j] = h; ll[j] = l; }
                }
                *(half8*)&As_h[row][k0 + q * 8] = hh;
                *(half8*)&As_l[row][k0 + q * 8] = ll;
            }
        }
        lgkm_barrier();
        const int icn = (ic + 1 == 5) ? 0 : ic + 1;
        if (i < 4) {                            // x prefetch for next chunk: flies across barriers now
#pragma unroll
            for (int q = 0; q < 8; ++q)
                *(uint4*)&pfw[q * 4] = *(const uint4*)(arow + icn * 64 + q * 4);
        }
        // MFMA phase: 4 slices, W double-buffered
#pragma unroll
        for (int sl4 = 0; sl4 < 4; ++sl4) {
            const int cur = sl4 & 1, nxt = cur ^ 1;
            if (sl4 < 3) {
                const int kq = ic * 8 + (sl4 + 1) * 2 + k8;
                const size_t wo = (size_t)(kq * 256 + no + n32) * 8;
                wbo_h[nxt] = *(const half8*)(Wh + wo);
                wbg_h[nxt] = *(const half8*)(Wh + wo + 1024);
                wbo_l[nxt] = *(const half8*)(Wl + wo);
                wbg_l[nxt] = *(const half8*)(Wl + wo + 1024);
            }
#pragma unroll
            for (int mt = 0; mt < 4; ++mt) {
                const half8 a_h = *(const half8*)&As_h[mt * 32 + n32][sl4 * 16 + k8 * 8];
                const half8 a_l = *(const half8*)&As_l[mt * 32 + n32][sl4 * 16 + k8 * 8];
                MFMA32(a_h, wbo_h[cur], accO[mt]); MFMA32(a_h, wbg_h[cur], accG[mt]);
                MFMA32(a_l, wbo_h[cur], accO[mt]); MFMA32(a_l, wbg_h[cur], accG[mt]);
                MFMA32(a_h, wbo_l[cur], accO[mt]); MFMA32(a_h, wbg_l[cur], accG[mt]);
            }
        }
        ic = icn;
    }
    lgkm_barrier();   // all As/mgs reads complete before H overlay writes

    // L1 epilogue -> H planes
    {
        const int c = no + n32;
        float sc_o, sh_o, sc_g, sh_g;
        bn_fold(bn1, b1, c, sc_o, sh_o);
        bn_fold(bn1, b1, c + 128, sc_g, sh_g);
#pragma unroll
        for (int mt = 0; mt < 4; ++mt)
#pragma unroll
            for (int q = 0; q < 4; ++q)
#pragma unroll
                for (int rp = 0; rp < 2; ++rp) {
                    const int r0 = q * 4 + rp * 2;
                    const int sl = mt * 32 + rp * 2 + 8 * q + 4 * k8;
                    const float y0 = glu_val(accO[mt][r0],     accG[mt][r0],     sc_o, sh_o, sc_g, sh_g);
                    const float y1 = glu_val(accO[mt][r0 + 1], accG[mt][r0 + 1], sc_o, sh_o, sc_g, sh_g);
                    half_t h0, l0, h1, l1;
                    split_pair(y0, y1, h0, l0, h1, l1);
                    H_h[sl][c] = h0; H_l[sl][c] = l0;
                    H_h[sl + 1][c] = h1; H_l[sl + 1][c] = l1;
                }
    }
    lgkm_barrier();

    // ---------------- L2, L3
#pragma unroll 1
    for (int layer = 0; layer < 2; ++layer) {
        const float* bb = layer ? b3 : b2;
        const float* bn = layer ? bn3 : bn2;
        const size_t off = layer ? w3_off : (size_t)81920;
#pragma unroll
        for (int i = 0; i < 4; ++i) { accO[i] = (floatx16)(0.f); accG[i] = (floatx16)(0.f); }
        layer_accum(H_h, H_l, Wh, Wl, off, n32, k8, no, half_id * 4, accO, accG);
        lgkm_barrier();
        {
            const int c = no + n32;
            float sc_o, sh_o, sc_g, sh_g;
            bn_fold(bn, bb, c, sc_o, sh_o);
            bn_fold(bn, bb, c + 128, sc_g, sh_g);
#pragma unroll
            for (int mt = 0; mt < 4; ++mt)
#pragma unroll
                for (int q = 0; q < 4; ++q)
#pragma unroll
                    for (int rp = 0; rp < 2; ++rp) {
                        const int r0 = q * 4 + rp * 2;
                        const int sl = mt * 32 + rp * 2 + 8 * q + 4 * k8;
                        const float res0 = (float)H_h[sl][c] + (float)H_l[sl][c];
                        const float res1 = (float)H_h[sl + 1][c] + (float)H_l[sl + 1][c];
                        const float y0 = (glu_val(accO[mt][r0],     accG[mt][r0],     sc_o, sh_o, sc_g, sh_g) + res0) * RES_SCALE_C;
                        const float y1 = (glu_val(accO[mt][r0 + 1], accG[mt][r0 + 1], sc_o, sh_o, sc_g, sh_g) + res1) * RES_SCALE_C;
                        half_t h0, l0, h1, l1;
                        split_pair(y0, y1, h0, l0, h1, l1);
                        H_h[sl][c] = h0; H_l[sl][c] = l0;
                        H_h[sl + 1][c] = h1; H_l[sl + 1][c] = l1;
                    }
        }
        lgkm_barrier();
    }

    // ---------------- L4 -> global outputs
#pragma unroll
    for (int i = 0; i < 4; ++i) { accO[i] = (floatx16)(0.f); accG[i] = (floatx16)(0.f); }
    layer_accum(H_h, H_l, Wh, Wl, w4_off, n32, k8, no, half_id * 4, accO, accG);
    {
        const int c = no + n32;
        float sc_o, sh_o, sc_g, sh_g;
        bn_fold(bn4, b4, c, sc_o, sh_o);
        bn_fold(bn4, b4, c + 128, sc_g, sh_g);
        if (w < 2) {
            if (wmode_last != 1) {
#pragma unroll
                for (int mt = 0; mt < 4; ++mt)
#pragma unroll
                    for (int reg = 0; reg < 16; ++reg) {
                        const int sl = mt * 32 + (reg & 3) + 8 * (reg >> 2) + 4 * k8;
                        const float res = (float)H_h[sl][c] + (float)H_l[sl][c];
                        const float y = (glu_val(accO[mt][reg], accG[mt][reg], sc_o, sh_o, sc_g, sh_g) + res) * RES_SCALE_C;
                        const float d = fmaxf(y, 0.f);
                        float* dp = ds + (size_t)(s0 + sl) * 64 + c;
                        *dp = (wmode_last == 2) ? d : (*dp + d);
                    }
            }
        } else {
#pragma unroll
            for (int mt = 0; mt < 4; ++mt)
#pragma unroll
                for (int q = 0; q < 4; ++q)
#pragma unroll
                    for (int rp = 0; rp < 2; ++rp) {
                        const int r0 = q * 4 + rp * 2;
                        const int sl = mt * 32 + rp * 2 + 8 * q + 4 * k8;
                        const float res0 = (float)H_h[sl][c] + (float)H_l[sl][c];
                        const float res1 = (float)H_h[sl + 1][c] + (float)H_l[sl + 1][c];
                        const float y0 = (glu_val(accO[mt][r0],     accG[mt][r0],     sc_o, sh_o, sc_g, sh_g) + res0) * RES_SCALE_C;
                        const float y1 = (glu_val(accO[mt][r0 + 1], accG[mt][r0 + 1], sc_o, sh_o, sc_g, sh_g) + res1) * RES_SCALE_C;
                        uint32_t w0, w1;
                        pack2_pair(y0, y1, w0, w1);
                        avp[(size_t)(s0 + sl) * 64 + (c - 64)] = w0;
                        avp[(size_t)(s0 + sl + 1) * 64 + (c - 64)] = w1;
                    }
        }
    }
}

// ---------------- final 64 -> 1 ----------------
__global__ void final_kernel(const float* __restrict__ dsum, const float* __restrict__ out_W,
                             const float* __restrict__ out_b, float* __restrict__ out)
{
    const int s = blockIdx.x * 256 + threadIdx.x;
    float acc = out_b[0];
    const float4* dp = (const float4*)(dsum + (size_t)s * 64);
    const float4* wp = (const float4*)out_W;
#pragma unroll
    for (int q = 0; q < 16; ++q) {
        const float4 d = dp[q];
        const float4 ww = wp[q];
        acc += d.x * ww.x + d.y * ww.y + d.z * ww.z + d.w * ww.w;
    }
    out[s] = acc;
}

// ---------------- launch ----------------
extern "C" void kernel_launch(void* const* d_in, const int* in_sizes, int n_in,
                              void* d_out, int out_size, void* d_ws, size_t ws_size,
                              hipStream_t stream)
{
    const float* x_num  = (const float*)d_in[0];
    const int*   x_cat  = (const int*)d_in[1];
    const float* emb_W  = (const float*)d_in[2];
    const float* in_bn  = (const float*)d_in[3];
    const float* sh_W0  = (const float*)d_in[4];
    const float* sh_b0  = (const float*)d_in[5];
    const float* sh_bn0 = (const float*)d_in[6];
    const float* sh_W1  = (const float*)d_in[7];
    const float* sh_b1  = (const float*)d_in[8];
    const float* sh_bn1 = (const float*)d_in[9];
    const float* init_W = (const float*)d_in[10];
    const float* init_b = (const float*)d_in[11];
    const float* init_bn= (const float*)d_in[12];
    const float* step_W = (const float*)d_in[13];
    const float* step_b = (const float*)d_in[14];
    const float* step_bn= (const float*)d_in[15];
    const float* att_W  = (const float*)d_in[16];
    const float* att_b  = (const float*)d_in[17];
    const float* att_bn = (const float*)d_in[18];
    const float* out_W  = (const float*)d_in[19];
    const float* out_b  = (const float*)d_in[20];

    const size_t B = B_TOT;
    char* p = (char*)d_ws;
    uint32_t* xp  = (uint32_t*)p;  p += B * 320 * 4;
    uint32_t* avp = (uint32_t*)p;  p += B * 64 * 4;
    half_t* Wh    = (half_t*)p;    p += 507904 * 2;
    half_t* Wl    = (half_t*)p;    p += 507904 * 2;
    half_t* aWh   = (half_t*)p;    p += 25600 * 2;
    half_t* aWl   = (half_t*)p;    p += 25600 * 2;
    float* pri    = (float*)p;     p += B * 80 * 4;
    float* ds     = (float*)p;     p += B * 64 * 4;

    wsplit_kernel<<<1984, 256, 0, stream>>>(sh_W0, sh_W1, init_W, step_W, Wh, Wl);
    wsplit_att_kernel<<<320, 80, 0, stream>>>(att_W, aWh, aWl);
    embed_bn_kernel<<<(B_TOT * 320) / 256, 256, 0, stream>>>(x_num, x_cat, emb_W, in_bn, xp);

    const int GB = B_TOT / 128;   // 512 blocks
    // W plane offsets (halves): sh_W0=0, sh_W1=81920, init0=114688, init1=147456, step j=180224+j*32768
    ft_chain<false><<<GB, 256, 0, stream>>>(xp, avp, Wh, Wl,
                                            nullptr, nullptr, nullptr, nullptr, nullptr,
                                            sh_b0, sh_bn0, sh_b1, sh_bn1,
                                            init_b, init_bn, init_b + 256, init_bn + 1024,
                                            (size_t)114688, (size_t)147456, ds, 1, 0);
    for (int st = 0; st < 5; ++st) {
        const size_t w3 = 180224 + (size_t)(st * 2 + 0) * 32768;
        const size_t w4 = 180224 + (size_t)(st * 2 + 1) * 32768;
        ft_chain<true><<<GB, 256, 0, stream>>>(xp, avp, Wh, Wl,
                                               aWh + st * 5120, aWl + st * 5120,
                                               att_b + st * 80, att_bn + st * 320, pri,
                                               sh_b0, sh_bn0, sh_b1, sh_bn1,
                                               step_b + (st * 2 + 0) * 256, step_bn + (st * 2 + 0) * 1024,
                                               step_b + (st * 2 + 1) * 256, step_bn + (st * 2 + 1) * 1024,
                                               w3, w4, ds, st == 0 ? 2 : 3, st);
    }
    final_kernel<<<B_TOT / 256, 256, 0, stream>>>(ds, out_W, out_b, (float*)d_out);
}

// Round 10
// 781.614 us; speedup vs baseline: 1.0993x; 1.0993x over previous
//
#include <hip/hip_runtime.h>
#include <math.h>
#include <stdint.h>

typedef _Float16 half_t;
typedef _Float16 half8 __attribute__((ext_vector_type(8)));
typedef __fp16 fp16x2 __attribute__((ext_vector_type(2)));
typedef float floatx4 __attribute__((ext_vector_type(4)));
typedef float floatx16 __attribute__((ext_vector_type(16)));

constexpr float BN_EPS_C = 1e-5f;
constexpr float RES_SCALE_C = 0.70710678118654752f;
constexpr float GAMMA_C = 1.5f;
#define B_TOT 65536

// ---------------- packed (hi,lo) fp16-pair helpers ----------------
__device__ __forceinline__ uint32_t pack2(float y) {
    const half_t h = (half_t)y;
    const half_t l = (half_t)(y - (float)h);
    union { half_t f; unsigned short u; } a, b; a.f = h; b.f = l;
    return (uint32_t)a.u | ((uint32_t)b.u << 16);
}
__device__ __forceinline__ void unpack2(uint32_t v, half_t& h, half_t& l) {
    union { unsigned short u; half_t f; } a, b;
    a.u = (unsigned short)(v & 0xffffu); b.u = (unsigned short)(v >> 16);
    h = a.f; l = b.f;
}
// paired split via packed RTZ converts (lo plane captures the residual; ~2^-21 rel)
__device__ __forceinline__ void split_pair(float y0, float y1, half_t& h0, half_t& l0, half_t& h1, half_t& l1) {
    fp16x2 hh = __builtin_amdgcn_cvt_pkrtz(y0, y1);
    fp16x2 ll = __builtin_amdgcn_cvt_pkrtz(y0 - (float)hh.x, y1 - (float)hh.y);
    h0 = (half_t)hh.x; l0 = (half_t)ll.x; h1 = (half_t)hh.y; l1 = (half_t)ll.y;
}
__device__ __forceinline__ void pack2_pair(float y0, float y1, uint32_t& w0, uint32_t& w1) {
    fp16x2 hh = __builtin_amdgcn_cvt_pkrtz(y0, y1);
    fp16x2 ll = __builtin_amdgcn_cvt_pkrtz(y0 - (float)hh.x, y1 - (float)hh.y);
    const uint32_t hb = __builtin_bit_cast(uint32_t, hh);
    const uint32_t lb = __builtin_bit_cast(uint32_t, ll);
    w0 = (hb & 0xffffu) | (lb << 16);
    w1 = (hb >> 16) | (lb & 0xffff0000u);
}

// ---------------- W split+repack (fragment-major 8-granule, hi/lo planes) ----------------
__global__ void wsplit_kernel(const float* __restrict__ sh_W0, const float* __restrict__ sh_W1,
                              const float* __restrict__ init_W, const float* __restrict__ step_W,
                              half_t* __restrict__ Wh, half_t* __restrict__ Wl)
{
    const int b = blockIdx.x, n = threadIdx.x;
    const float* src; int k; size_t base;
    if (b < 320)      { src = sh_W0;           k = b;       base = 0; }
    else if (b < 448) { src = sh_W1;           k = b - 320; base = 81920; }
    else if (b < 576) { src = init_W;          k = b - 448; base = 114688; }
    else if (b < 704) { src = init_W + 32768;  k = b - 576; base = 147456; }
    else {
        int j = (b - 704) >> 7; k = (b - 704) & 127;
        src = step_W + (size_t)j * 32768; base = 180224 + (size_t)j * 32768;
    }
    const float v = src[k * 256 + n];
    const half_t hi = (half_t)v;
    const half_t lo = (half_t)(v - (float)hi);
    const size_t idx = base + (size_t)(((k >> 3) * 256 + n) * 8 + (k & 7));
    Wh[idx] = hi; Wl[idx] = lo;
}

__global__ void wsplit_att_kernel(const float* __restrict__ att_W,
                                  half_t* __restrict__ aWh, half_t* __restrict__ aWl)
{
    const int b = blockIdx.x;        // step*64 + k
    const int n = threadIdx.x;       // 0..79
    const int step = b >> 6, k = b & 63;
    const float v = att_W[(size_t)b * 80 + n];
    const half_t h = (half_t)v;
    const half_t l = (half_t)(v - (float)h);
    const size_t idx = (size_t)step * 5120 + (size_t)(((k >> 3) * 80 + n) * 8 + (k & 7));
    aWh[idx] = h; aWl[idx] = l;
}

__global__ void embed_bn_kernel(const float* __restrict__ x_num, const int* __restrict__ x_cat,
                                const float* __restrict__ emb_W, const float* __restrict__ in_bn,
                                uint32_t* __restrict__ xp)
{
    const int idx = blockIdx.x * 256 + threadIdx.x;
    const int s = idx / 320, j = idx - s * 320;
    float v;
    if (j < 64) v = x_num[(size_t)s * 64 + j];
    else {
        const int c = (j - 64) >> 4, e = (j - 64) & 15;
        v = emb_W[(size_t)(c * 1000 + x_cat[(size_t)s * 16 + c]) * 16 + e];
    }
    const float val = (v - in_bn[640 + j]) * (in_bn[j] * __frsqrt_rn(in_bn[960 + j] + BN_EPS_C)) + in_bn[320 + j];
    xp[idx] = pack2(val);
}

__device__ __forceinline__ void bn_fold(const float* __restrict__ bn, const float* __restrict__ bias,
                                        int c, float& sc, float& sh)
{
    sc = bn[c] * __frsqrt_rn(bn[768 + c] + BN_EPS_C);
    sh = fmaf(bias[c] - bn[512 + c], sc, bn[256 + c]);
}

__device__ __forceinline__ float glu_val(float accO, float accG,
                                         float sc_o, float sh_o, float sc_g, float sh_g)
{
    const float o = fmaf(accO, sc_o, sh_o);
    const float g = fmaf(accG, sc_g, sh_g);
    const float e = __expf(-g);
    return o * __builtin_amdgcn_rcpf(1.f + e);
}

#define MFMA32(A, B, C) C = __builtin_amdgcn_mfma_f32_32x32x16_f16(A, B, C, 0, 0, 0)
#define MFMA16(A, B, C) C = __builtin_amdgcn_mfma_f32_16x16x32_f16(A, B, C, 0, 0, 0)

// K=128 layer accumulate from H planes (8 slices of 16-k, rotated start)
__device__ __forceinline__ void layer_accum(const half_t (*H_h)[136], const half_t (*H_l)[136],
                                            const half_t* __restrict__ Wh, const half_t* __restrict__ Wl,
                                            size_t off, int n32, int k8, int no, int rot,
                                            floatx16* accO, floatx16* accG)
{
#pragma unroll 2
    for (int s = 0; s < 8; ++s) {
        const int sl8 = (s + rot) & 7;
        const int kq = sl8 * 2 + k8;
        const size_t wo = off + (size_t)(kq * 256 + no + n32) * 8;
        const half8 bo_h = *(const half8*)(Wh + wo);
        const half8 bo_l = *(const half8*)(Wl + wo);
        const half8 bg_h = *(const half8*)(Wh + wo + 1024);
        const half8 bg_l = *(const half8*)(Wl + wo + 1024);
#pragma unroll
        for (int mt = 0; mt < 4; ++mt) {
            const half8 a_h = *(const half8*)&H_h[mt * 32 + n32][sl8 * 16 + k8 * 8];
            const half8 a_l = *(const half8*)&H_l[mt * 32 + n32][sl8 * 16 + k8 * 8];
            MFMA32(a_h, bo_h, accO[mt]); MFMA32(a_h, bg_h, accG[mt]);
            MFMA32(a_l, bo_h, accO[mt]); MFMA32(a_l, bg_h, accG[mt]);
            MFMA32(a_h, bo_l, accO[mt]); MFMA32(a_h, bg_l, accG[mt]);
        }
    }
}

// ---------------- fused (att+sparsemax) + FT chain, 128 samples/block ----------------
template<bool MASK>
__global__ __launch_bounds__(256, 2)
void ft_chain(const uint32_t* __restrict__ xp, uint32_t* __restrict__ avp,
              const half_t* __restrict__ Wh, const half_t* __restrict__ Wl,
              const half_t* __restrict__ aWh, const half_t* __restrict__ aWl,
              const float* __restrict__ att_b, const float* __restrict__ att_bn,
              float* __restrict__ prior,
              const float* __restrict__ b1, const float* __restrict__ bn1,
              const float* __restrict__ b2, const float* __restrict__ bn2,
              const float* __restrict__ b3, const float* __restrict__ bn3,
              const float* __restrict__ b4, const float* __restrict__ bn4,
              size_t w3_off, size_t w4_off,
              float* __restrict__ ds, int wmode_last, int step)
{
    // LDS region plan (79872 B total, overlaid in time):
    //  [0,43008)        mgs float[128][84]      (mask; live att-z -> end of L1 staging)
    //  [43008,79872)    As planes [128][72]x2   (L1 chunk tile) / Apk uint32[128][68] (att stage)
    //  [0,69632)        H planes [128][136]x2   (written at L1 epilogue, after all above dead)
    __shared__ __align__(16) char smem[79872];
    float    (*mgs)[84]  = (float    (*)[84])smem;
    half_t   (*As_h)[72] = (half_t   (*)[72])(smem + 43008);
    half_t   (*As_l)[72] = (half_t   (*)[72])(smem + 61440);
    uint32_t (*Apk)[68]  = (uint32_t (*)[68])(smem + 43008);
    half_t   (*H_h)[136] = (half_t   (*)[136])smem;
    half_t   (*H_l)[136] = (half_t   (*)[136])(smem + 34816);

    const int t = threadIdx.x;
    const int s0 = blockIdx.x * 128;
    const int w = t >> 6, lane = t & 63;
    const int n32 = lane & 31, k8 = lane >> 5;
    const int quad = lane >> 4, l16 = lane & 15;
    const int no = 32 * w;
    const int half_id = (blockIdx.x >> 8) & 1;
    const int row = t >> 1, k0 = (t & 1) * 32;

    if (MASK) {
        // ---- stage avp (packed) -> Apk
        {
            const uint4* src = (const uint4*)(avp + (size_t)(s0 + row) * 64 + k0);
            uint4* dst = (uint4*)&Apk[row][k0];
#pragma unroll
            for (int q = 0; q < 8; ++q) dst[q] = src[q];
        }
        __syncthreads();
        // ---- z = BN(a@attW + b) * prior
        floatx4 zacc[2][5];
#pragma unroll
        for (int mt = 0; mt < 2; ++mt)
#pragma unroll
            for (int nt = 0; nt < 5; ++nt) zacc[mt][nt] = (floatx4){0.f, 0.f, 0.f, 0.f};
#pragma unroll
        for (int kc = 0; kc < 64; kc += 32) {
            half8 a_h[2], a_l[2];
#pragma unroll
            for (int mt = 0; mt < 2; ++mt) {
                uint32_t wv[8];
                *(uint4*)&wv[0] = *(const uint4*)&Apk[w * 32 + mt * 16 + l16][kc + quad * 8];
                *(uint4*)&wv[4] = *(const uint4*)&Apk[w * 32 + mt * 16 + l16][kc + quad * 8 + 4];
#pragma unroll
                for (int j = 0; j < 8; ++j) { half_t h, l; unpack2(wv[j], h, l); a_h[mt][j] = h; a_l[mt][j] = l; }
            }
            const int kq = (kc >> 3) + quad;
#pragma unroll
            for (int nt = 0; nt < 5; ++nt) {
                const size_t wi = (size_t)(kq * 80 + nt * 16 + l16) * 8;
                const half8 b_h = *(const half8*)(aWh + wi);
                const half8 b_l = *(const half8*)(aWl + wi);
#pragma unroll
                for (int mt = 0; mt < 2; ++mt) {
                    MFMA16(a_h[mt], b_h, zacc[mt][nt]);
                    MFMA16(a_l[mt], b_h, zacc[mt][nt]);
                    MFMA16(a_h[mt], b_l, zacc[mt][nt]);
                }
            }
        }
        float preg[2][5][4];
#pragma unroll
        for (int nt = 0; nt < 5; ++nt) {
            const int c = nt * 16 + l16;
            const float sc = att_bn[c] * __frsqrt_rn(att_bn[240 + c] + BN_EPS_C);
            const float sh = fmaf(att_b[c] - att_bn[160 + c], sc, att_bn[80 + c]);
#pragma unroll
            for (int mt = 0; mt < 2; ++mt)
#pragma unroll
                for (int r = 0; r < 4; ++r) {
                    const int sl = w * 32 + mt * 16 + quad * 4 + r;
                    const float pr = (step == 0) ? 1.f : prior[(size_t)(s0 + sl) * 80 + c];
                    preg[mt][nt][r] = pr;
                    mgs[sl][c] = fmaf(zacc[mt][nt][r], sc, sh) * pr;
                }
        }
        __syncthreads();
        // ---- bisection sparsemax: 2 threads/sample, 40 groups each (16 iters: tau err ~2^-17)
        {
            const int samp = row, j0 = (t & 1) * 40;
            float zj[40], zmax = -1e30f;
#pragma unroll
            for (int j = 0; j < 40; ++j) { zj[j] = mgs[samp][j0 + j]; zmax = fmaxf(zmax, zj[j]); }
            zmax = fmaxf(zmax, __shfl_xor(zmax, 1));
            float lo = zmax - 1.f, hi = zmax;
#pragma unroll 1
            for (int it = 0; it < 16; ++it) {
                const float mid = 0.5f * (lo + hi);
                float ssum = 0.f;
#pragma unroll
                for (int j = 0; j < 40; ++j) ssum += fmaxf(zj[j] - mid, 0.f);
                ssum += __shfl_xor(ssum, 1);
                if (ssum >= 1.f) lo = mid; else hi = mid;
            }
            const float tau = 0.5f * (lo + hi);
#pragma unroll
            for (int j = 0; j < 40; ++j) mgs[samp][j0 + j] = fmaxf(zj[j] - tau, 0.f);
        }
        __syncthreads();
        // ---- prior update
#pragma unroll
        for (int nt = 0; nt < 5; ++nt) {
            const int c = nt * 16 + l16;
#pragma unroll
            for (int mt = 0; mt < 2; ++mt)
#pragma unroll
                for (int r = 0; r < 4; ++r) {
                    const int sl = w * 32 + mt * 16 + quad * 4 + r;
                    prior[(size_t)(s0 + sl) * 80 + c] = preg[mt][nt][r] * (GAMMA_C - mgs[sl][c]);
                }
        }
    }

    // ---------------- L1: K=320 (5 chunks of 64), masked staging, prefetched
    floatx16 accO[4], accG[4];
#pragma unroll
    for (int i = 0; i < 4; ++i) { accO[i] = (floatx16)(0.f); accG[i] = (floatx16)(0.f); }

    const uint32_t* arow = xp + (size_t)(s0 + row) * 320 + k0;
    uint32_t pfw[32];
    int ic = half_id * 2;
#pragma unroll
    for (int q = 0; q < 8; ++q)
        *(uint4*)&pfw[q * 4] = *(const uint4*)(arow + ic * 64 + q * 4);

#pragma unroll 1
    for (int i = 0; i < 5; ++i) {
        __syncthreads();                       // prev chunk reads (and att Apk reads) done
        {
            const int kb = ic * 64 + k0;
            float mA = 1.f, mB = 1.f;
            if (MASK && ic != 0) {
                mA = mgs[row][64 + ((kb - 64) >> 4)];
                mB = mgs[row][64 + ((kb - 48) >> 4)];
            }
#pragma unroll
            for (int q = 0; q < 4; ++q) {
                half8 hh, ll;
                if (MASK && ic == 0) {
                    const float4 m0q = *(const float4*)&mgs[row][kb + q * 8];
                    const float4 m1q = *(const float4*)&mgs[row][kb + q * 8 + 4];
                    const float mm[8] = {m0q.x, m0q.y, m0q.z, m0q.w, m1q.x, m1q.y, m1q.z, m1q.w};
#pragma unroll
                    for (int j = 0; j < 8; ++j) {
                        half_t h, l; unpack2(pfw[q * 8 + j], h, l);
                        const float v = ((float)h + (float)l) * mm[j];
                        const half_t nh = (half_t)v;
                        hh[j] = nh; ll[j] = (half_t)(v - (float)nh);
                    }
                } else if (MASK) {
                    const float m = (q < 2) ? mA : mB;
#pragma unroll
                    for (int j = 0; j < 8; ++j) {
                        half_t h, l; unpack2(pfw[q * 8 + j], h, l);
                        const float v = ((float)h + (float)l) * m;
                        const half_t nh = (half_t)v;
                        hh[j] = nh; ll[j] = (half_t)(v - (float)nh);
                    }
                } else {
#pragma unroll
                    for (int j = 0; j < 8; ++j) { half_t h, l; unpack2(pfw[q * 8 + j], h, l); hh[j] = h; ll[j] = l; }
                }
                *(half8*)&As_h[row][k0 + q * 8] = hh;
                *(half8*)&As_l[row][k0 + q * 8] = ll;
            }
        }
        __syncthreads();
        const int icn = (ic + 1 == 5) ? 0 : ic + 1;
        if (i < 4) {                            // x prefetch for next chunk
#pragma unroll
            for (int q = 0; q < 8; ++q)
                *(uint4*)&pfw[q * 4] = *(const uint4*)(arow + icn * 64 + q * 4);
        }
#pragma unroll
        for (int sl4 = 0; sl4 < 4; ++sl4) {
            const int kq = ic * 8 + sl4 * 2 + k8;
            const size_t wo = (size_t)(kq * 256 + no + n32) * 8;
            const half8 bo_h = *(const half8*)(Wh + wo);
            const half8 bo_l = *(const half8*)(Wl + wo);
            const half8 bg_h = *(const half8*)(Wh + wo + 1024);
            const half8 bg_l = *(const half8*)(Wl + wo + 1024);
#pragma unroll
            for (int mt = 0; mt < 4; ++mt) {
                const half8 a_h = *(const half8*)&As_h[mt * 32 + n32][sl4 * 16 + k8 * 8];
                const half8 a_l = *(const half8*)&As_l[mt * 32 + n32][sl4 * 16 + k8 * 8];
                MFMA32(a_h, bo_h, accO[mt]); MFMA32(a_h, bg_h, accG[mt]);
                MFMA32(a_l, bo_h, accO[mt]); MFMA32(a_l, bg_h, accG[mt]);
                MFMA32(a_h, bo_l, accO[mt]); MFMA32(a_h, bg_l, accG[mt]);
            }
        }
        ic = icn;
    }
    __syncthreads();   // all As/mgs reads complete before H overlay writes

    // L1 epilogue -> H planes (paired pkrtz split)
    {
        const int c = no + n32;
        float sc_o, sh_o, sc_g, sh_g;
        bn_fold(bn1, b1, c, sc_o, sh_o);
        bn_fold(bn1, b1, c + 128, sc_g, sh_g);
#pragma unroll
        for (int mt = 0; mt < 4; ++mt)
#pragma unroll
            for (int q = 0; q < 4; ++q)
#pragma unroll
                for (int rp = 0; rp < 2; ++rp) {
                    const int r0 = q * 4 + rp * 2;
                    const int sl = mt * 32 + rp * 2 + 8 * q + 4 * k8;
                    const float y0 = glu_val(accO[mt][r0],     accG[mt][r0],     sc_o, sh_o, sc_g, sh_g);
                    const float y1 = glu_val(accO[mt][r0 + 1], accG[mt][r0 + 1], sc_o, sh_o, sc_g, sh_g);
                    half_t h0, l0, h1, l1;
                    split_pair(y0, y1, h0, l0, h1, l1);
                    H_h[sl][c] = h0; H_l[sl][c] = l0;
                    H_h[sl + 1][c] = h1; H_l[sl + 1][c] = l1;
                }
    }
    __syncthreads();

    // ---------------- L2, L3
#pragma unroll 1
    for (int layer = 0; layer < 2; ++layer) {
        const float* bb = layer ? b3 : b2;
        const float* bn = layer ? bn3 : bn2;
        const size_t off = layer ? w3_off : (size_t)81920;
#pragma unroll
        for (int i = 0; i < 4; ++i) { accO[i] = (floatx16)(0.f); accG[i] = (floatx16)(0.f); }
        layer_accum(H_h, H_l, Wh, Wl, off, n32, k8, no, half_id * 4, accO, accG);
        __syncthreads();
        {
            const int c = no + n32;
            float sc_o, sh_o, sc_g, sh_g;
            bn_fold(bn, bb, c, sc_o, sh_o);
            bn_fold(bn, bb, c + 128, sc_g, sh_g);
#pragma unroll
            for (int mt = 0; mt < 4; ++mt)
#pragma unroll
                for (int q = 0; q < 4; ++q)
#pragma unroll
                    for (int rp = 0; rp < 2; ++rp) {
                        const int r0 = q * 4 + rp * 2;
                        const int sl = mt * 32 + rp * 2 + 8 * q + 4 * k8;
                        const float res0 = (float)H_h[sl][c] + (float)H_l[sl][c];
                        const float res1 = (float)H_h[sl + 1][c] + (float)H_l[sl + 1][c];
                        const float y0 = (glu_val(accO[mt][r0],     accG[mt][r0],     sc_o, sh_o, sc_g, sh_g) + res0) * RES_SCALE_C;
                        const float y1 = (glu_val(accO[mt][r0 + 1], accG[mt][r0 + 1], sc_o, sh_o, sc_g, sh_g) + res1) * RES_SCALE_C;
                        half_t h0, l0, h1, l1;
                        split_pair(y0, y1, h0, l0, h1, l1);
                        H_h[sl][c] = h0; H_l[sl][c] = l0;
                        H_h[sl + 1][c] = h1; H_l[sl + 1][c] = l1;
                    }
        }
        __syncthreads();
    }

    // ---------------- L4 -> global outputs
#pragma unroll
    for (int i = 0; i < 4; ++i) { accO[i] = (floatx16)(0.f); accG[i] = (floatx16)(0.f); }
    layer_accum(H_h, H_l, Wh, Wl, w4_off, n32, k8, no, half_id * 4, accO, accG);
    {
        const int c = no + n32;
        float sc_o, sh_o, sc_g, sh_g;
        bn_fold(bn4, b4, c, sc_o, sh_o);
        bn_fold(bn4, b4, c + 128, sc_g, sh_g);
        if (w < 2) {
            if (wmode_last != 1) {
#pragma unroll
                for (int mt = 0; mt < 4; ++mt)
#pragma unroll
                    for (int reg = 0; reg < 16; ++reg) {
                        const int sl = mt * 32 + (reg & 3) + 8 * (reg >> 2) + 4 * k8;
                        const float res = (float)H_h[sl][c] + (float)H_l[sl][c];
                        const float y = (glu_val(accO[mt][reg], accG[mt][reg], sc_o, sh_o, sc_g, sh_g) + res) * RES_SCALE_C;
                        const float d = fmaxf(y, 0.f);
                        float* dp = ds + (size_t)(s0 + sl) * 64 + c;
                        *dp = (wmode_last == 2) ? d : (*dp + d);
                    }
            }
        } else {
#pragma unroll
            for (int mt = 0; mt < 4; ++mt)
#pragma unroll
                for (int q = 0; q < 4; ++q)
#pragma unroll
                    for (int rp = 0; rp < 2; ++rp) {
                        const int r0 = q * 4 + rp * 2;
                        const int sl = mt * 32 + rp * 2 + 8 * q + 4 * k8;
                        const float res0 = (float)H_h[sl][c] + (float)H_l[sl][c];
                        const float res1 = (float)H_h[sl + 1][c] + (float)H_l[sl + 1][c];
                        const float y0 = (glu_val(accO[mt][r0],     accG[mt][r0],     sc_o, sh_o, sc_g, sh_g) + res0) * RES_SCALE_C;
                        const float y1 = (glu_val(accO[mt][r0 + 1], accG[mt][r0 + 1], sc_o, sh_o, sc_g, sh_g) + res1) * RES_SCALE_C;
                        uint32_t w0, w1;
                        pack2_pair(y0, y1, w0, w1);
                        avp[(size_t)(s0 + sl) * 64 + (c - 64)] = w0;
                        avp[(size_t)(s0 + sl + 1) * 64 + (c - 64)] = w1;
                    }
        }
    }
}

// ---------------- final 64 -> 1 ----------------
__global__ void final_kernel(const float* __restrict__ dsum, const float* __restrict__ out_W,
                             const float* __restrict__ out_b, float* __restrict__ out)
{
    const int s = blockIdx.x * 256 + threadIdx.x;
    float acc = out_b[0];
    const float4* dp = (const float4*)(dsum + (size_t)s * 64);
    const float4* wp = (const float4*)out_W;
#pragma unroll
    for (int q = 0; q < 16; ++q) {
        const float4 d = dp[q];
        const float4 ww = wp[q];
        acc += d.x * ww.x + d.y * ww.y + d.z * ww.z + d.w * ww.w;
    }
    out[s] = acc;
}

// ---------------- launch ----------------
extern "C" void kernel_launch(void* const* d_in, const int* in_sizes, int n_in,
                              void* d_out, int out_size, void* d_ws, size_t ws_size,
                              hipStream_t stream)
{
    const float* x_num  = (const float*)d_in[0];
    const int*   x_cat  = (const int*)d_in[1];
    const float* emb_W  = (const float*)d_in[2];
    const float* in_bn  = (const float*)d_in[3];
    const float* sh_W0  = (const float*)d_in[4];
    const float* sh_b0  = (const float*)d_in[5];
    const float* sh_bn0 = (const float*)d_in[6];
    const float* sh_W1  = (const float*)d_in[7];
    const float* sh_b1  = (const float*)d_in[8];
    const float* sh_bn1 = (const float*)d_in[9];
    const float* init_W = (const float*)d_in[10];
    const float* init_b = (const float*)d_in[11];
    const float* init_bn= (const float*)d_in[12];
    const float* step_W = (const float*)d_in[13];
    const float* step_b = (const float*)d_in[14];
    const float* step_bn= (const float*)d_in[15];
    const float* att_W  = (const float*)d_in[16];
    const float* att_b  = (const float*)d_in[17];
    const float* att_bn = (const float*)d_in[18];
    const float* out_W  = (const float*)d_in[19];
    const float* out_b  = (const float*)d_in[20];

    const size_t B = B_TOT;
    char* p = (char*)d_ws;
    uint32_t* xp  = (uint32_t*)p;  p += B * 320 * 4;
    uint32_t* avp = (uint32_t*)p;  p += B * 64 * 4;
    half_t* Wh    = (half_t*)p;    p += 507904 * 2;
    half_t* Wl    = (half_t*)p;    p += 507904 * 2;
    half_t* aWh   = (half_t*)p;    p += 25600 * 2;
    half_t* aWl   = (half_t*)p;    p += 25600 * 2;
    float* pri    = (float*)p;     p += B * 80 * 4;
    float* ds     = (float*)p;     p += B * 64 * 4;

    wsplit_kernel<<<1984, 256, 0, stream>>>(sh_W0, sh_W1, init_W, step_W, Wh, Wl);
    wsplit_att_kernel<<<320, 80, 0, stream>>>(att_W, aWh, aWl);
    embed_bn_kernel<<<(B_TOT * 320) / 256, 256, 0, stream>>>(x_num, x_cat, emb_W, in_bn, xp);

    const int GB = B_TOT / 128;   // 512 blocks
    // W plane offsets (halves): sh_W0=0, sh_W1=81920, init0=114688, init1=147456, step j=180224+j*32768
    ft_chain<false><<<GB, 256, 0, stream>>>(xp, avp, Wh, Wl,
                                            nullptr, nullptr, nullptr, nullptr, nullptr,
                                            sh_b0, sh_bn0, sh_b1, sh_bn1,
                                            init_b, init_bn, init_b + 256, init_bn + 1024,
                                            (size_t)114688, (size_t)147456, ds, 1, 0);
    for (int st = 0; st < 5; ++st) {
        const size_t w3 = 180224 + (size_t)(st * 2 + 0) * 32768;
        const size_t w4 = 180224 + (size_t)(st * 2 + 1) * 32768;
        ft_chain<true><<<GB, 256, 0, stream>>>(xp, avp, Wh, Wl,
                                               aWh + st * 5120, aWl + st * 5120,
                                               att_b + st * 80, att_bn + st * 320, pri,
                                               sh_b0, sh_bn0, sh_b1, sh_bn1,
                                               step_b + (st * 2 + 0) * 256, step_bn + (st * 2 + 0) * 1024,
                                               step_b + (st * 2 + 1) * 256, step_bn + (st * 2 + 1) * 1024,
                                               w3, w4, ds, st == 0 ? 2 : 3, st);
    }
    final_kernel<<<B_TOT / 256, 256, 0, stream>>>(ds, out_W, out_b, (float*)d_out);
}

// Round 11
// 733.273 us; speedup vs baseline: 1.1717x; 1.0659x over previous
//
#include <hip/hip_runtime.h>
#include <math.h>
#include <stdint.h>

typedef _Float16 half_t;
typedef _Float16 half8 __attribute__((ext_vector_type(8)));
typedef __fp16 fp16x2 __attribute__((ext_vector_type(2)));
typedef float floatx4 __attribute__((ext_vector_type(4)));
typedef float floatx16 __attribute__((ext_vector_type(16)));

constexpr float BN_EPS_C = 1e-5f;
constexpr float RES_SCALE_C = 0.70710678118654752f;
constexpr float GAMMA_C = 1.5f;
#define B_TOT 65536

// ---------------- packed (hi,lo) fp16-pair helpers ----------------
__device__ __forceinline__ uint32_t pack2(float y) {
    const half_t h = (half_t)y;
    const half_t l = (half_t)(y - (float)h);
    union { half_t f; unsigned short u; } a, b; a.f = h; b.f = l;
    return (uint32_t)a.u | ((uint32_t)b.u << 16);
}
__device__ __forceinline__ void unpack2(uint32_t v, half_t& h, half_t& l) {
    union { unsigned short u; half_t f; } a, b;
    a.u = (unsigned short)(v & 0xffffu); b.u = (unsigned short)(v >> 16);
    h = a.f; l = b.f;
}
__device__ __forceinline__ void split_pair(float y0, float y1, half_t& h0, half_t& l0, half_t& h1, half_t& l1) {
    fp16x2 hh = __builtin_amdgcn_cvt_pkrtz(y0, y1);
    fp16x2 ll = __builtin_amdgcn_cvt_pkrtz(y0 - (float)hh.x, y1 - (float)hh.y);
    h0 = (half_t)hh.x; l0 = (half_t)ll.x; h1 = (half_t)hh.y; l1 = (half_t)ll.y;
}
__device__ __forceinline__ void pack2_pair(float y0, float y1, uint32_t& w0, uint32_t& w1) {
    fp16x2 hh = __builtin_amdgcn_cvt_pkrtz(y0, y1);
    fp16x2 ll = __builtin_amdgcn_cvt_pkrtz(y0 - (float)hh.x, y1 - (float)hh.y);
    const uint32_t hb = __builtin_bit_cast(uint32_t, hh);
    const uint32_t lb = __builtin_bit_cast(uint32_t, ll);
    w0 = (hb & 0xffffu) | (lb << 16);
    w1 = (hb >> 16) | (lb & 0xffff0000u);
}

// ---------------- W split+repack (fragment-major 8-granule, hi/lo planes) ----------------
__global__ void wsplit_kernel(const float* __restrict__ sh_W0, const float* __restrict__ sh_W1,
                              const float* __restrict__ init_W, const float* __restrict__ step_W,
                              half_t* __restrict__ Wh, half_t* __restrict__ Wl)
{
    const int b = blockIdx.x, n = threadIdx.x;
    const float* src; int k; size_t base;
    if (b < 320)      { src = sh_W0;           k = b;       base = 0; }
    else if (b < 448) { src = sh_W1;           k = b - 320; base = 81920; }
    else if (b < 576) { src = init_W;          k = b - 448; base = 114688; }
    else if (b < 704) { src = init_W + 32768;  k = b - 576; base = 147456; }
    else {
        int j = (b - 704) >> 7; k = (b - 704) & 127;
        src = step_W + (size_t)j * 32768; base = 180224 + (size_t)j * 32768;
    }
    const float v = src[k * 256 + n];
    const half_t hi = (half_t)v;
    const half_t lo = (half_t)(v - (float)hi);
    const size_t idx = base + (size_t)(((k >> 3) * 256 + n) * 8 + (k & 7));
    Wh[idx] = hi; Wl[idx] = lo;
}

__global__ void wsplit_att_kernel(const float* __restrict__ att_W,
                                  half_t* __restrict__ aWh, half_t* __restrict__ aWl)
{
    const int b = blockIdx.x;        // step*64 + k
    const int n = threadIdx.x;       // 0..79
    const int step = b >> 6, k = b & 63;
    const float v = att_W[(size_t)b * 80 + n];
    const half_t h = (half_t)v;
    const half_t l = (half_t)(v - (float)h);
    const size_t idx = (size_t)step * 5120 + (size_t)(((k >> 3) * 80 + n) * 8 + (k & 7));
    aWh[idx] = h; aWl[idx] = l;
}

__global__ void embed_bn_kernel(const float* __restrict__ x_num, const int* __restrict__ x_cat,
                                const float* __restrict__ emb_W, const float* __restrict__ in_bn,
                                uint32_t* __restrict__ xp)
{
    const int idx = blockIdx.x * 256 + threadIdx.x;
    const int s = idx / 320, j = idx - s * 320;
    float v;
    if (j < 64) v = x_num[(size_t)s * 64 + j];
    else {
        const int c = (j - 64) >> 4, e = (j - 64) & 15;
        v = emb_W[(size_t)(c * 1000 + x_cat[(size_t)s * 16 + c]) * 16 + e];
    }
    const float val = (v - in_bn[640 + j]) * (in_bn[j] * __frsqrt_rn(in_bn[960 + j] + BN_EPS_C)) + in_bn[320 + j];
    xp[idx] = pack2(val);
}

__device__ __forceinline__ void bn_fold(const float* __restrict__ bn, const float* __restrict__ bias,
                                        int c, float& sc, float& sh)
{
    sc = bn[c] * __frsqrt_rn(bn[768 + c] + BN_EPS_C);
    sh = fmaf(bias[c] - bn[512 + c], sc, bn[256 + c]);
}

__device__ __forceinline__ float glu_val(float accO, float accG,
                                         float sc_o, float sh_o, float sc_g, float sh_g)
{
    const float o = fmaf(accO, sc_o, sh_o);
    const float g = fmaf(accG, sc_g, sh_g);
    const float e = __expf(-g);
    return o * __builtin_amdgcn_rcpf(1.f + e);
}

#define MFMA32(A, B, C) C = __builtin_amdgcn_mfma_f32_32x32x16_f16(A, B, C, 0, 0, 0)
#define MFMA16(A, B, C) C = __builtin_amdgcn_mfma_f32_16x16x32_f16(A, B, C, 0, 0, 0)

// K=128 layer accumulate from H planes (8 slices of 16-k, rotated start); wave owns 2 m-tiles.
__device__ __forceinline__ void layer_accum(const half_t (*H_h)[136], const half_t (*H_l)[136],
                                            const half_t* __restrict__ Wh, const half_t* __restrict__ Wl,
                                            size_t off, int n32, int k8, int no, int m0, int rot,
                                            floatx16* accO, floatx16* accG)
{
#pragma unroll 2
    for (int s = 0; s < 8; ++s) {
        const int sl8 = (s + rot) & 7;
        const int kq = sl8 * 2 + k8;
        const size_t wo = off + (size_t)(kq * 256 + no + n32) * 8;
        const half8 bo_h = *(const half8*)(Wh + wo);
        const half8 bo_l = *(const half8*)(Wl + wo);
        const half8 bg_h = *(const half8*)(Wh + wo + 1024);
        const half8 bg_l = *(const half8*)(Wl + wo + 1024);
#pragma unroll
        for (int mt = 0; mt < 2; ++mt) {
            const half8 a_h = *(const half8*)&H_h[m0 + mt * 32 + n32][sl8 * 16 + k8 * 8];
            const half8 a_l = *(const half8*)&H_l[m0 + mt * 32 + n32][sl8 * 16 + k8 * 8];
            MFMA32(a_h, bo_h, accO[mt]); MFMA32(a_h, bg_h, accG[mt]);
            MFMA32(a_l, bo_h, accO[mt]); MFMA32(a_l, bg_h, accG[mt]);
            MFMA32(a_h, bo_l, accO[mt]); MFMA32(a_h, bg_l, accG[mt]);
        }
    }
}

// ---------------- fused (att+sparsemax) + FT chain, 128 samples/block, 512 threads / 8 waves ----------------
template<bool MASK>
__global__ __launch_bounds__(512, 4)
void ft_chain(const uint32_t* __restrict__ xp, uint32_t* __restrict__ avp,
              const half_t* __restrict__ Wh, const half_t* __restrict__ Wl,
              const half_t* __restrict__ aWh, const half_t* __restrict__ aWl,
              const float* __restrict__ att_b, const float* __restrict__ att_bn,
              float* __restrict__ prior,
              const float* __restrict__ b1, const float* __restrict__ bn1,
              const float* __restrict__ b2, const float* __restrict__ bn2,
              const float* __restrict__ b3, const float* __restrict__ bn3,
              const float* __restrict__ b4, const float* __restrict__ bn4,
              size_t w3_off, size_t w4_off,
              float* __restrict__ ds, int wmode_last, int step)
{
    // LDS overlay (79872 B): mgs [0,43008); As planes at 43008/61440; Apk at 43008;
    // H planes at 0/34816 (written after mgs/As/Apk dead).
    __shared__ __align__(16) char smem[79872];
    float    (*mgs)[84]  = (float    (*)[84])smem;
    half_t   (*As_h)[72] = (half_t   (*)[72])(smem + 43008);
    half_t   (*As_l)[72] = (half_t   (*)[72])(smem + 61440);
    uint32_t (*Apk)[68]  = (uint32_t (*)[68])(smem + 43008);
    half_t   (*H_h)[136] = (half_t   (*)[136])smem;
    half_t   (*H_l)[136] = (half_t   (*)[136])(smem + 34816);

    const int t = threadIdx.x;
    const int s0 = blockIdx.x * 128;
    const int w = t >> 6, lane = t & 63;
    const int wq = w & 3, wh = w >> 2;        // col-group, sample-half
    const int n32 = lane & 31, k8 = lane >> 5;
    const int quad = lane >> 4, l16 = lane & 15;
    const int no = 32 * wq;
    const int m0 = wh * 64;
    const int half_id = (blockIdx.x >> 8) & 1;
    const int rowA = t >> 2, kA = (t & 3) * 16;   // staging: 16 words/thread

    if (MASK) {
        // ---- stage avp (packed) -> Apk
        {
            const uint4* src = (const uint4*)(avp + (size_t)(s0 + rowA) * 64 + kA);
            uint4* dst = (uint4*)&Apk[rowA][kA];
#pragma unroll
            for (int q = 0; q < 4; ++q) dst[q] = src[q];
        }
        __syncthreads();
        // ---- z = BN(a@attW + b) * prior  (wave w owns m-tile w: samples w*16..w*16+16)
        floatx4 zacc[5];
#pragma unroll
        for (int nt = 0; nt < 5; ++nt) zacc[nt] = (floatx4){0.f, 0.f, 0.f, 0.f};
#pragma unroll
        for (int kc = 0; kc < 64; kc += 32) {
            uint32_t wv[8];
            *(uint4*)&wv[0] = *(const uint4*)&Apk[w * 16 + l16][kc + quad * 8];
            *(uint4*)&wv[4] = *(const uint4*)&Apk[w * 16 + l16][kc + quad * 8 + 4];
            half8 a_h, a_l;
#pragma unroll
            for (int j = 0; j < 8; ++j) { half_t h, l; unpack2(wv[j], h, l); a_h[j] = h; a_l[j] = l; }
            const int kq = (kc >> 3) + quad;
#pragma unroll
            for (int nt = 0; nt < 5; ++nt) {
                const size_t wi = (size_t)(kq * 80 + nt * 16 + l16) * 8;
                const half8 b_h = *(const half8*)(aWh + wi);
                const half8 b_l = *(const half8*)(aWl + wi);
                MFMA16(a_h, b_h, zacc[nt]);
                MFMA16(a_l, b_h, zacc[nt]);
                MFMA16(a_h, b_l, zacc[nt]);
            }
        }
        float preg[5][4];
#pragma unroll
        for (int nt = 0; nt < 5; ++nt) {
            const int c = nt * 16 + l16;
            const float sc = att_bn[c] * __frsqrt_rn(att_bn[240 + c] + BN_EPS_C);
            const float sh = fmaf(att_b[c] - att_bn[160 + c], sc, att_bn[80 + c]);
#pragma unroll
            for (int r = 0; r < 4; ++r) {
                const int sl = w * 16 + quad * 4 + r;
                const float pr = (step == 0) ? 1.f : prior[(size_t)(s0 + sl) * 80 + c];
                preg[nt][r] = pr;
                mgs[sl][c] = fmaf(zacc[nt][r], sc, sh) * pr;
            }
        }
        __syncthreads();
        // ---- bisection sparsemax: 4 threads/sample, 20 groups each (16 iters)
        {
            const int samp = rowA, j0 = (t & 3) * 20;
            float zj[20], zmax = -1e30f;
#pragma unroll
            for (int j = 0; j < 20; ++j) { zj[j] = mgs[samp][j0 + j]; zmax = fmaxf(zmax, zj[j]); }
            zmax = fmaxf(zmax, __shfl_xor(zmax, 1));
            zmax = fmaxf(zmax, __shfl_xor(zmax, 2));
            float lo = zmax - 1.f, hi = zmax;
#pragma unroll 1
            for (int it = 0; it < 16; ++it) {
                const float mid = 0.5f * (lo + hi);
                float ssum = 0.f;
#pragma unroll
                for (int j = 0; j < 20; ++j) ssum += fmaxf(zj[j] - mid, 0.f);
                ssum += __shfl_xor(ssum, 1);
                ssum += __shfl_xor(ssum, 2);
                if (ssum >= 1.f) lo = mid; else hi = mid;
            }
            const float tau = 0.5f * (lo + hi);
#pragma unroll
            for (int j = 0; j < 20; ++j) mgs[samp][j0 + j] = fmaxf(zj[j] - tau, 0.f);
        }
        __syncthreads();
        // ---- prior update (wave w, m-tile w)
#pragma unroll
        for (int nt = 0; nt < 5; ++nt) {
            const int c = nt * 16 + l16;
#pragma unroll
            for (int r = 0; r < 4; ++r) {
                const int sl = w * 16 + quad * 4 + r;
                prior[(size_t)(s0 + sl) * 80 + c] = preg[nt][r] * (GAMMA_C - mgs[sl][c]);
            }
        }
    }

    // ---------------- L1: K=320 (5 chunks of 64), masked staging, prefetched
    floatx16 accO[2], accG[2];
#pragma unroll
    for (int i = 0; i < 2; ++i) { accO[i] = (floatx16)(0.f); accG[i] = (floatx16)(0.f); }

    const uint32_t* arow = xp + (size_t)(s0 + rowA) * 320 + kA;
    uint32_t pfw[16];
    int ic = half_id * 2;
#pragma unroll
    for (int q = 0; q < 4; ++q)
        *(uint4*)&pfw[q * 4] = *(const uint4*)(arow + ic * 64 + q * 4);

#pragma unroll 1
    for (int i = 0; i < 5; ++i) {
        __syncthreads();                       // prev chunk reads (and att Apk reads) done
        {
            const int kb = ic * 64 + kA;
            float mG = 1.f;
            if (MASK && ic != 0) mG = mgs[rowA][64 + ((kb - 64) >> 4)];
#pragma unroll
            for (int q = 0; q < 2; ++q) {
                half8 hh, ll;
                if (MASK && ic == 0) {
#pragma unroll
                    for (int j = 0; j < 8; ++j) {
                        half_t h, l; unpack2(pfw[q * 8 + j], h, l);
                        const float v = ((float)h + (float)l) * mgs[rowA][kb + q * 8 + j];
                        const half_t nh = (half_t)v;
                        hh[j] = nh; ll[j] = (half_t)(v - (float)nh);
                    }
                } else if (MASK) {
#pragma unroll
                    for (int j = 0; j < 8; ++j) {
                        half_t h, l; unpack2(pfw[q * 8 + j], h, l);
                        const float v = ((float)h + (float)l) * mG;
                        const half_t nh = (half_t)v;
                        hh[j] = nh; ll[j] = (half_t)(v - (float)nh);
                    }
                } else {
#pragma unroll
                    for (int j = 0; j < 8; ++j) { half_t h, l; unpack2(pfw[q * 8 + j], h, l); hh[j] = h; ll[j] = l; }
                }
                *(half8*)&As_h[rowA][kA + q * 8] = hh;
                *(half8*)&As_l[rowA][kA + q * 8] = ll;
            }
        }
        __syncthreads();
        const int icn = (ic + 1 == 5) ? 0 : ic + 1;
        if (i < 4) {                            // x prefetch for next chunk
#pragma unroll
            for (int q = 0; q < 4; ++q)
                *(uint4*)&pfw[q * 4] = *(const uint4*)(arow + icn * 64 + q * 4);
        }
#pragma unroll
        for (int sl4 = 0; sl4 < 4; ++sl4) {
            const int kq = ic * 8 + sl4 * 2 + k8;
            const size_t wo = (size_t)(kq * 256 + no + n32) * 8;
            const half8 bo_h = *(const half8*)(Wh + wo);
            const half8 bo_l = *(const half8*)(Wl + wo);
            const half8 bg_h = *(const half8*)(Wh + wo + 1024);
            const half8 bg_l = *(const half8*)(Wl + wo + 1024);
#pragma unroll
            for (int mt = 0; mt < 2; ++mt) {
                const half8 a_h = *(const half8*)&As_h[m0 + mt * 32 + n32][sl4 * 16 + k8 * 8];
                const half8 a_l = *(const half8*)&As_l[m0 + mt * 32 + n32][sl4 * 16 + k8 * 8];
                MFMA32(a_h, bo_h, accO[mt]); MFMA32(a_h, bg_h, accG[mt]);
                MFMA32(a_l, bo_h, accO[mt]); MFMA32(a_l, bg_h, accG[mt]);
                MFMA32(a_h, bo_l, accO[mt]); MFMA32(a_h, bg_l, accG[mt]);
            }
        }
        ic = icn;
    }
    __syncthreads();   // all As/mgs reads complete before H overlay writes

    // L1 epilogue -> H planes (paired pkrtz split)
    {
        const int c = no + n32;
        float sc_o, sh_o, sc_g, sh_g;
        bn_fold(bn1, b1, c, sc_o, sh_o);
        bn_fold(bn1, b1, c + 128, sc_g, sh_g);
#pragma unroll
        for (int mt = 0; mt < 2; ++mt)
#pragma unroll
            for (int q = 0; q < 4; ++q)
#pragma unroll
                for (int rp = 0; rp < 2; ++rp) {
                    const int r0 = q * 4 + rp * 2;
                    const int sl = m0 + mt * 32 + rp * 2 + 8 * q + 4 * k8;
                    const float y0 = glu_val(accO[mt][r0],     accG[mt][r0],     sc_o, sh_o, sc_g, sh_g);
                    const float y1 = glu_val(accO[mt][r0 + 1], accG[mt][r0 + 1], sc_o, sh_o, sc_g, sh_g);
                    half_t h0, l0, h1, l1;
                    split_pair(y0, y1, h0, l0, h1, l1);
                    H_h[sl][c] = h0; H_l[sl][c] = l0;
                    H_h[sl + 1][c] = h1; H_l[sl + 1][c] = l1;
                }
    }
    __syncthreads();

    // ---------------- L2, L3
#pragma unroll 1
    for (int layer = 0; layer < 2; ++layer) {
        const float* bb = layer ? b3 : b2;
        const float* bn = layer ? bn3 : bn2;
        const size_t off = layer ? w3_off : (size_t)81920;
#pragma unroll
        for (int i = 0; i < 2; ++i) { accO[i] = (floatx16)(0.f); accG[i] = (floatx16)(0.f); }
        layer_accum(H_h, H_l, Wh, Wl, off, n32, k8, no, m0, half_id * 4, accO, accG);
        __syncthreads();
        {
            const int c = no + n32;
            float sc_o, sh_o, sc_g, sh_g;
            bn_fold(bn, bb, c, sc_o, sh_o);
            bn_fold(bn, bb, c + 128, sc_g, sh_g);
#pragma unroll
            for (int mt = 0; mt < 2; ++mt)
#pragma unroll
                for (int q = 0; q < 4; ++q)
#pragma unroll
                    for (int rp = 0; rp < 2; ++rp) {
                        const int r0 = q * 4 + rp * 2;
                        const int sl = m0 + mt * 32 + rp * 2 + 8 * q + 4 * k8;
                        const float res0 = (float)H_h[sl][c] + (float)H_l[sl][c];
                        const float res1 = (float)H_h[sl + 1][c] + (float)H_l[sl + 1][c];
                        const float y0 = (glu_val(accO[mt][r0],     accG[mt][r0],     sc_o, sh_o, sc_g, sh_g) + res0) * RES_SCALE_C;
                        const float y1 = (glu_val(accO[mt][r0 + 1], accG[mt][r0 + 1], sc_o, sh_o, sc_g, sh_g) + res1) * RES_SCALE_C;
                        half_t h0, l0, h1, l1;
                        split_pair(y0, y1, h0, l0, h1, l1);
                        H_h[sl][c] = h0; H_l[sl][c] = l0;
                        H_h[sl + 1][c] = h1; H_l[sl + 1][c] = l1;
                    }
        }
        __syncthreads();
    }

    // ---------------- L4 -> global outputs
#pragma unroll
    for (int i = 0; i < 2; ++i) { accO[i] = (floatx16)(0.f); accG[i] = (floatx16)(0.f); }
    layer_accum(H_h, H_l, Wh, Wl, w4_off, n32, k8, no, m0, half_id * 4, accO, accG);
    {
        const int c = no + n32;
        float sc_o, sh_o, sc_g, sh_g;
        bn_fold(bn4, b4, c, sc_o, sh_o);
        bn_fold(bn4, b4, c + 128, sc_g, sh_g);
        if (wq < 2) {
            if (wmode_last != 1) {
#pragma unroll
                for (int mt = 0; mt < 2; ++mt)
#pragma unroll
                    for (int reg = 0; reg < 16; ++reg) {
                        const int sl = m0 + mt * 32 + (reg & 3) + 8 * (reg >> 2) + 4 * k8;
                        const float res = (float)H_h[sl][c] + (float)H_l[sl][c];
                        const float y = (glu_val(accO[mt][reg], accG[mt][reg], sc_o, sh_o, sc_g, sh_g) + res) * RES_SCALE_C;
                        const float d = fmaxf(y, 0.f);
                        float* dp = ds + (size_t)(s0 + sl) * 64 + c;
                        *dp = (wmode_last == 2) ? d : (*dp + d);
                    }
            }
        } else {
#pragma unroll
            for (int mt = 0; mt < 2; ++mt)
#pragma unroll
                for (int q = 0; q < 4; ++q)
#pragma unroll
                    for (int rp = 0; rp < 2; ++rp) {
                        const int r0 = q * 4 + rp * 2;
                        const int sl = m0 + mt * 32 + rp * 2 + 8 * q + 4 * k8;
                        const float res0 = (float)H_h[sl][c] + (float)H_l[sl][c];
                        const float res1 = (float)H_h[sl + 1][c] + (float)H_l[sl + 1][c];
                        const float y0 = (glu_val(accO[mt][r0],     accG[mt][r0],     sc_o, sh_o, sc_g, sh_g) + res0) * RES_SCALE_C;
                        const float y1 = (glu_val(accO[mt][r0 + 1], accG[mt][r0 + 1], sc_o, sh_o, sc_g, sh_g) + res1) * RES_SCALE_C;
                        uint32_t w0, w1;
                        pack2_pair(y0, y1, w0, w1);
                        avp[(size_t)(s0 + sl) * 64 + (c - 64)] = w0;
                        avp[(size_t)(s0 + sl + 1) * 64 + (c - 64)] = w1;
                    }
        }
    }
}

// ---------------- final 64 -> 1 ----------------
__global__ void final_kernel(const float* __restrict__ dsum, const float* __restrict__ out_W,
                             const float* __restrict__ out_b, float* __restrict__ out)
{
    const int s = blockIdx.x * 256 + threadIdx.x;
    float acc = out_b[0];
    const float4* dp = (const float4*)(dsum + (size_t)s * 64);
    const float4* wp = (const float4*)out_W;
#pragma unroll
    for (int q = 0; q < 16; ++q) {
        const float4 d = dp[q];
        const float4 ww = wp[q];
        acc += d.x * ww.x + d.y * ww.y + d.z * ww.z + d.w * ww.w;
    }
    out[s] = acc;
}

// ---------------- launch ----------------
extern "C" void kernel_launch(void* const* d_in, const int* in_sizes, int n_in,
                              void* d_out, int out_size, void* d_ws, size_t ws_size,
                              hipStream_t stream)
{
    const float* x_num  = (const float*)d_in[0];
    const int*   x_cat  = (const int*)d_in[1];
    const float* emb_W  = (const float*)d_in[2];
    const float* in_bn  = (const float*)d_in[3];
    const float* sh_W0  = (const float*)d_in[4];
    const float* sh_b0  = (const float*)d_in[5];
    const float* sh_bn0 = (const float*)d_in[6];
    const float* sh_W1  = (const float*)d_in[7];
    const float* sh_b1  = (const float*)d_in[8];
    const float* sh_bn1 = (const float*)d_in[9];
    const float* init_W = (const float*)d_in[10];
    const float* init_b = (const float*)d_in[11];
    const float* init_bn= (const float*)d_in[12];
    const float* step_W = (const float*)d_in[13];
    const float* step_b = (const float*)d_in[14];
    const float* step_bn= (const float*)d_in[15];
    const float* att_W  = (const float*)d_in[16];
    const float* att_b  = (const float*)d_in[17];
    const float* att_bn = (const float*)d_in[18];
    const float* out_W  = (const float*)d_in[19];
    const float* out_b  = (const float*)d_in[20];

    const size_t B = B_TOT;
    char* p = (char*)d_ws;
    uint32_t* xp  = (uint32_t*)p;  p += B * 320 * 4;
    uint32_t* avp = (uint32_t*)p;  p += B * 64 * 4;
    half_t* Wh    = (half_t*)p;    p += 507904 * 2;
    half_t* Wl    = (half_t*)p;    p += 507904 * 2;
    half_t* aWh   = (half_t*)p;    p += 25600 * 2;
    half_t* aWl   = (half_t*)p;    p += 25600 * 2;
    float* pri    = (float*)p;     p += B * 80 * 4;
    float* ds     = (float*)p;     p += B * 64 * 4;

    wsplit_kernel<<<1984, 256, 0, stream>>>(sh_W0, sh_W1, init_W, step_W, Wh, Wl);
    wsplit_att_kernel<<<320, 80, 0, stream>>>(att_W, aWh, aWl);
    embed_bn_kernel<<<(B_TOT * 320) / 256, 256, 0, stream>>>(x_num, x_cat, emb_W, in_bn, xp);

    const int GB = B_TOT / 128;   // 512 blocks
    // W plane offsets (halves): sh_W0=0, sh_W1=81920, init0=114688, init1=147456, step j=180224+j*32768
    ft_chain<false><<<GB, 512, 0, stream>>>(xp, avp, Wh, Wl,
                                            nullptr, nullptr, nullptr, nullptr, nullptr,
                                            sh_b0, sh_bn0, sh_b1, sh_bn1,
                                            init_b, init_bn, init_b + 256, init_bn + 1024,
                                            (size_t)114688, (size_t)147456, ds, 1, 0);
    for (int st = 0; st < 5; ++st) {
        const size_t w3 = 180224 + (size_t)(st * 2 + 0) * 32768;
        const size_t w4 = 180224 + (size_t)(st * 2 + 1) * 32768;
        ft_chain<true><<<GB, 512, 0, stream>>>(xp, avp, Wh, Wl,
                                               aWh + st * 5120, aWl + st * 5120,
                                               att_b + st * 80, att_bn + st * 320, pri,
                                               sh_b0, sh_bn0, sh_b1, sh_bn1,
                                               step_b + (st * 2 + 0) * 256, step_bn + (st * 2 + 0) * 1024,
                                               step_b + (st * 2 + 1) * 256, step_bn + (st * 2 + 1) * 1024,
                                               w3, w4, ds, st == 0 ? 2 : 3, st);
    }
    final_kernel<<<B_TOT / 256, 256, 0, stream>>>(ds, out_W, out_b, (float*)d_out);
}